// Round 1
// baseline (305.238 us; speedup 1.0000x reference)
//
#include <hip/hip_runtime.h>

// ---------------------------------------------------------------------------
// maskselfattention: B=2, S=2048, D=1024, H=16, hd=64
// Pipeline: convert x,W to bf16 (W transposed) -> fused QKV GEMM (bf16 MFMA,
// fp32 acc) writing Q,K as [b][h][s][64] and V transposed [b][h][64][s]
// -> causal flash attention (bf16 MFMA, online softmax fp32).
// ---------------------------------------------------------------------------

typedef unsigned short u16;
typedef __bf16 bf16x8 __attribute__((ext_vector_type(8)));
typedef float f32x4 __attribute__((ext_vector_type(4)));
typedef u16 u16x8 __attribute__((ext_vector_type(8)));

#define NB 2
#define NS 2048
#define ND 1024
#define NH 16
#define HD 64

__device__ __forceinline__ u16 f2bf(float f) {
    unsigned int u = __float_as_uint(f);
    unsigned int r = u + 0x7fffu + ((u >> 16) & 1u);
    return (u16)(r >> 16);
}

__device__ __forceinline__ f32x4 mfma16(bf16x8 a, bf16x8 b, f32x4 c) {
    return __builtin_amdgcn_mfma_f32_16x16x32_bf16(a, b, c, 0, 0, 0);
}

__device__ __forceinline__ void gl_lds16(const void* g, void* l) {
    __builtin_amdgcn_global_load_lds(
        (const __attribute__((address_space(1))) unsigned int*)g,
        (__attribute__((address_space(3))) unsigned int*)l, 16, 0, 0);
}

// --- x (fp32) -> xb (bf16), elementwise, 8 elems/thread -------------------
__global__ __launch_bounds__(256) void convx_k(const float* __restrict__ x,
                                               u16* __restrict__ xb) {
    int i = (blockIdx.x * 256 + threadIdx.x) * 8;
    const float4* p = (const float4*)(x + i);
    float4 a = p[0], c = p[1];
    u16x8 r;
    r[0] = f2bf(a.x); r[1] = f2bf(a.y); r[2] = f2bf(a.z); r[3] = f2bf(a.w);
    r[4] = f2bf(c.x); r[5] = f2bf(c.y); r[6] = f2bf(c.z); r[7] = f2bf(c.w);
    *(u16x8*)(xb + i) = r;
}

// --- W [k][n] fp32 -> Wt [z][n][k] bf16 (transpose via LDS tile) ----------
__global__ __launch_bounds__(256) void convw_k(const float* __restrict__ wq,
                                               const float* __restrict__ wk,
                                               const float* __restrict__ wv,
                                               u16* __restrict__ wt) {
    __shared__ float tile[32][33];
    const int z = blockIdx.z;
    const float* W = (z == 0) ? wq : (z == 1) ? wk : wv;
    const int k0 = blockIdx.x * 32, n0 = blockIdx.y * 32;
    const int tx = threadIdx.x & 31, ty = threadIdx.x >> 5;  // 32x8
#pragma unroll
    for (int rr = 0; rr < 32; rr += 8)
        tile[ty + rr][tx] = W[(size_t)(k0 + ty + rr) * ND + n0 + tx];
    __syncthreads();
    u16* dst = wt + (size_t)z * ND * ND;
#pragma unroll
    for (int rr = 0; rr < 32; rr += 8)
        dst[(size_t)(n0 + ty + rr) * ND + k0 + tx] = f2bf(tile[tx][ty + rr]);
}

// --- fused QKV GEMM: C = xb @ W (z=0:Q, 1:K, 2:V) --------------------------
// 128x128 tile, BK=32, 256 threads (4 waves, each 64x64).
// z<2: writes [b][h][s][64]; z==2: computes C^T directly (swapped mfma
// operands) and writes Vt [b][h][64][s].
__global__ __launch_bounds__(256) void qkv_gemm_k(const u16* __restrict__ xb,
                                                  const u16* __restrict__ wt,
                                                  u16* __restrict__ qh,
                                                  u16* __restrict__ kh,
                                                  u16* __restrict__ vt) {
    __shared__ u16 At[128 * 32];
    __shared__ u16 Bt[128 * 32];
    const int z = blockIdx.z;
    const int m0 = blockIdx.x * 128;
    const int n0 = blockIdx.y * 128;
    const u16* w = wt + (size_t)z * ND * ND;
    const int t = threadIdx.x;
    const int lane = t & 63;
    const int wv = t >> 6;
    const int wm = (wv >> 1) * 64, wn = (wv & 1) * 64;
    const int fr = lane & 15;  // fragment row within 16
    const int ks = lane >> 4;  // k sub-slice (8 elems each)

    f32x4 acc[4][4] = {};

    const int g0 = t, g1 = 256 + t;
    const int r0 = g0 >> 2, c0 = (g0 & 3) * 8;
    const int r1 = g1 >> 2, c1 = (g1 & 3) * 8;

    for (int kt = 0; kt < ND; kt += 32) {
        // stage A (xb tile) and B (Wt tile): 16B per call, lds = base+lane*16
        gl_lds16(xb + (size_t)(m0 + r0) * ND + kt + c0, (char*)At + g0 * 16);
        gl_lds16(xb + (size_t)(m0 + r1) * ND + kt + c1, (char*)At + g1 * 16);
        gl_lds16(w + (size_t)(n0 + r0) * ND + kt + c0, (char*)Bt + g0 * 16);
        gl_lds16(w + (size_t)(n0 + r1) * ND + kt + c1, (char*)Bt + g1 * 16);
        __syncthreads();

        bf16x8 fa[4], fb[4];
#pragma unroll
        for (int i = 0; i < 4; i++)
            fa[i] = *(const bf16x8*)&At[(wm + i * 16 + fr) * 32 + ks * 8];
#pragma unroll
        for (int j = 0; j < 4; j++)
            fb[j] = *(const bf16x8*)&Bt[(wn + j * 16 + fr) * 32 + ks * 8];

        if (z < 2) {
#pragma unroll
            for (int i = 0; i < 4; i++)
#pragma unroll
                for (int j = 0; j < 4; j++)
                    acc[i][j] = mfma16(fa[i], fb[j], acc[i][j]);
        } else {
#pragma unroll
            for (int i = 0; i < 4; i++)
#pragma unroll
                for (int j = 0; j < 4; j++)
                    acc[i][j] = mfma16(fb[j], fa[i], acc[i][j]);
        }
        __syncthreads();
    }

    if (z < 2) {
        u16* dst = (z == 0) ? qh : kh;
#pragma unroll
        for (int i = 0; i < 4; i++)
#pragma unroll
            for (int j = 0; j < 4; j++)
#pragma unroll
                for (int r = 0; r < 4; r++) {
                    int mg = m0 + wm + i * 16 + ks * 4 + r;
                    int ng = n0 + wn + j * 16 + fr;
                    int b = mg >> 11, s = mg & 2047;
                    int hh = ng >> 6, dd = ng & 63;
                    dst[(((size_t)b * NH + hh) * NS + s) * HD + dd] =
                        f2bf(acc[i][j][r]);
                }
    } else {
#pragma unroll
        for (int i = 0; i < 4; i++)
#pragma unroll
            for (int j = 0; j < 4; j++)
#pragma unroll
                for (int r = 0; r < 4; r++) {
                    int ng = n0 + wn + j * 16 + ks * 4 + r;  // d-dim
                    int mg = m0 + wm + i * 16 + fr;          // s-dim
                    int b = mg >> 11, s = mg & 2047;
                    int hh = ng >> 6, dd = ng & 63;
                    vt[(((size_t)b * NH + hh) * HD + dd) * NS + s] =
                        f2bf(acc[i][j][r]);
                }
    }
}

// --- causal flash attention ------------------------------------------------
// grid: (S/64, B*H). 256 threads = 4 waves; wave w owns q rows
// [qt + 16w, qt + 16w + 16). kv tiles of 32, trip count per wave (causal).
__global__ __launch_bounds__(256) void attn_k(const u16* __restrict__ qh,
                                              const u16* __restrict__ kh,
                                              const u16* __restrict__ vt,
                                              float* __restrict__ out) {
    const int t = threadIdx.x, lane = t & 63, wv = t >> 6;
    const int fr = lane & 15, ks = lane >> 4;
    const int bh = blockIdx.y, b = bh >> 4, h = bh & 15;
    const int qt = blockIdx.x * 64;
    const int q0 = qt + wv * 16;
    const u16* Q = qh + (size_t)bh * NS * HD;
    const u16* K = kh + (size_t)bh * NS * HD;
    const u16* V = vt + (size_t)bh * HD * NS;

    bf16x8 fq0 = *(const bf16x8*)&Q[(q0 + fr) * HD + ks * 8];
    bf16x8 fq1 = *(const bf16x8*)&Q[(q0 + fr) * HD + 32 + ks * 8];

    float m[4] = {-1e30f, -1e30f, -1e30f, -1e30f};
    float lsum[4] = {0.f, 0.f, 0.f, 0.f};
    f32x4 o[4] = {};

    __shared__ u16 Pl[4][16 * 32];
    u16* pl = &Pl[wv][0];

    const int ntile = (q0 + 16 + 31) >> 5;  // causal: kv0 <= q0+15
    for (int kt2 = 0; kt2 < ntile; ++kt2) {
        const int kv0 = kt2 * 32;
        f32x4 sc[2] = {};
        {
            bf16x8 fk00 = *(const bf16x8*)&K[(kv0 + fr) * HD + ks * 8];
            bf16x8 fk01 = *(const bf16x8*)&K[(kv0 + fr) * HD + 32 + ks * 8];
            bf16x8 fk10 = *(const bf16x8*)&K[(kv0 + 16 + fr) * HD + ks * 8];
            bf16x8 fk11 = *(const bf16x8*)&K[(kv0 + 16 + fr) * HD + 32 + ks * 8];
            sc[0] = mfma16(fq0, fk00, sc[0]);
            sc[0] = mfma16(fq1, fk01, sc[0]);
            sc[1] = mfma16(fq0, fk10, sc[1]);
            sc[1] = mfma16(fq1, fk11, sc[1]);
        }
#pragma unroll
        for (int r = 0; r < 4; r++) {
            const int qg = q0 + ks * 4 + r;
            float v0 = sc[0][r] * 0.125f;
            float v1 = sc[1][r] * 0.125f;
            if (kv0 + fr > qg) v0 = -1e30f;
            if (kv0 + 16 + fr > qg) v1 = -1e30f;
            float pm = fmaxf(v0, v1);
            pm = fmaxf(pm, __shfl_xor(pm, 1));
            pm = fmaxf(pm, __shfl_xor(pm, 2));
            pm = fmaxf(pm, __shfl_xor(pm, 4));
            pm = fmaxf(pm, __shfl_xor(pm, 8));
            float mn = fmaxf(m[r], pm);
            float co = __expf(m[r] - mn);
            float p0 = __expf(v0 - mn);
            float p1 = __expf(v1 - mn);
            float rs = p0 + p1;
            rs += __shfl_xor(rs, 1);
            rs += __shfl_xor(rs, 2);
            rs += __shfl_xor(rs, 4);
            rs += __shfl_xor(rs, 8);
            lsum[r] = lsum[r] * co + rs;
            m[r] = mn;
            o[0][r] *= co;
            o[1][r] *= co;
            o[2][r] *= co;
            o[3][r] *= co;
            pl[(ks * 4 + r) * 32 + fr] = f2bf(p0);
            pl[(ks * 4 + r) * 32 + 16 + fr] = f2bf(p1);
        }
        // re-fragment P (wave-private LDS; compiler inserts lgkm waits)
        bf16x8 fp = *(const bf16x8*)&pl[fr * 32 + ks * 8];
#pragma unroll
        for (int j = 0; j < 4; j++) {
            bf16x8 fv = *(const bf16x8*)&V[(j * 16 + fr) * NS + kv0 + ks * 8];
            o[j] = mfma16(fp, fv, o[j]);
        }
    }

#pragma unroll
    for (int j = 0; j < 4; j++)
#pragma unroll
        for (int r = 0; r < 4; r++) {
            const int qg = q0 + ks * 4 + r;
            out[((size_t)b * NS + qg) * ND + h * HD + j * 16 + fr] =
                o[j][r] / lsum[r];
        }
}

extern "C" void kernel_launch(void* const* d_in, const int* in_sizes, int n_in,
                              void* d_out, int out_size, void* d_ws,
                              size_t ws_size, hipStream_t stream) {
    const float* x = (const float*)d_in[0];
    const float* wq = (const float*)d_in[1];
    const float* wk = (const float*)d_in[2];
    const float* wvp = (const float*)d_in[3];
    float* out = (float*)d_out;

    char* w8 = (char*)d_ws;
    u16* xb = (u16*)(w8);                               // 8 MiB
    u16* wt = (u16*)(w8 + ((size_t)8 << 20));           // 6 MiB
    u16* qh = (u16*)(w8 + ((size_t)14 << 20));          // 8 MiB
    u16* kh = (u16*)(w8 + ((size_t)22 << 20));          // 8 MiB
    u16* vt = (u16*)(w8 + ((size_t)30 << 20));          // 8 MiB

    convx_k<<<(NB * NS * ND) / (256 * 8), 256, 0, stream>>>(x, xb);
    convw_k<<<dim3(ND / 32, ND / 32, 3), 256, 0, stream>>>(wq, wk, wvp, wt);
    qkv_gemm_k<<<dim3((NB * NS) / 128, ND / 128, 3), 256, 0, stream>>>(
        xb, wt, qh, kh, vt);
    attn_k<<<dim3(NS / 64, NB * NH), 256, 0, stream>>>(qh, kh, vt, out);
}

// Round 2
// 180.719 us; speedup vs baseline: 1.6890x; 1.6890x over previous
//
#include <hip/hip_runtime.h>

// ---------------------------------------------------------------------------
// maskselfattention: B=2, S=2048, D=1024, H=16, hd=64
// convert x,W to bf16 (W transposed) -> fused QKV GEMM (bf16 MFMA, fp32 acc)
// writing Q,K as [b][h][s][64] and V transposed [b][h][64][s] -> causal flash
// attention (bf16 MFMA, online softmax fp32, paired q-tiles for balance).
// ---------------------------------------------------------------------------

typedef unsigned short u16;
typedef __bf16 bf16x8 __attribute__((ext_vector_type(8)));
typedef float f32x4 __attribute__((ext_vector_type(4)));
typedef u16 u16x8 __attribute__((ext_vector_type(8)));

#define NB 2
#define NS 2048
#define ND 1024
#define NH 16
#define HD 64

__device__ __forceinline__ u16 f2bf(float f) {
    unsigned int u = __float_as_uint(f);
    unsigned int r = u + 0x7fffu + ((u >> 16) & 1u);
    return (u16)(r >> 16);
}

__device__ __forceinline__ f32x4 mfma16(bf16x8 a, bf16x8 b, f32x4 c) {
    return __builtin_amdgcn_mfma_f32_16x16x32_bf16(a, b, c, 0, 0, 0);
}

__device__ __forceinline__ void gl_lds16(const void* g, void* l) {
    __builtin_amdgcn_global_load_lds(
        (const __attribute__((address_space(1))) unsigned int*)g,
        (__attribute__((address_space(3))) unsigned int*)l, 16, 0, 0);
}

// --- x (fp32) -> xb (bf16) -------------------------------------------------
__global__ __launch_bounds__(256) void convx_k(const float* __restrict__ x,
                                               u16* __restrict__ xb) {
    int i = (blockIdx.x * 256 + threadIdx.x) * 8;
    const float4* p = (const float4*)(x + i);
    float4 a = p[0], c = p[1];
    u16x8 r;
    r[0] = f2bf(a.x); r[1] = f2bf(a.y); r[2] = f2bf(a.z); r[3] = f2bf(a.w);
    r[4] = f2bf(c.x); r[5] = f2bf(c.y); r[6] = f2bf(c.z); r[7] = f2bf(c.w);
    *(u16x8*)(xb + i) = r;
}

// --- W [k][n] fp32 -> Wt [z][n][k] bf16 ------------------------------------
__global__ __launch_bounds__(256) void convw_k(const float* __restrict__ wq,
                                               const float* __restrict__ wk,
                                               const float* __restrict__ wv,
                                               u16* __restrict__ wt) {
    __shared__ float tile[32][33];
    const int z = blockIdx.z;
    const float* W = (z == 0) ? wq : (z == 1) ? wk : wv;
    const int k0 = blockIdx.x * 32, n0 = blockIdx.y * 32;
    const int tx = threadIdx.x & 31, ty = threadIdx.x >> 5;
#pragma unroll
    for (int rr = 0; rr < 32; rr += 8)
        tile[ty + rr][tx] = W[(size_t)(k0 + ty + rr) * ND + n0 + tx];
    __syncthreads();
    u16* dst = wt + (size_t)z * ND * ND;
#pragma unroll
    for (int rr = 0; rr < 32; rr += 8)
        dst[(size_t)(n0 + ty + rr) * ND + k0 + tx] = f2bf(tile[tx][ty + rr]);
}

// --- fused QKV GEMM --------------------------------------------------------
__global__ __launch_bounds__(256) void qkv_gemm_k(const u16* __restrict__ xb,
                                                  const u16* __restrict__ wt,
                                                  u16* __restrict__ qh,
                                                  u16* __restrict__ kh,
                                                  u16* __restrict__ vt) {
    __shared__ u16 At[128 * 32];
    __shared__ u16 Bt[128 * 32];
    const int z = blockIdx.z;
    const int m0 = blockIdx.x * 128;
    const int n0 = blockIdx.y * 128;
    const u16* w = wt + (size_t)z * ND * ND;
    const int t = threadIdx.x;
    const int lane = t & 63;
    const int wv = t >> 6;
    const int wm = (wv >> 1) * 64, wn = (wv & 1) * 64;
    const int fr = lane & 15;
    const int ks = lane >> 4;

    f32x4 acc[4][4] = {};

    const int g0 = t, g1 = 256 + t;
    const int r0 = g0 >> 2, c0 = (g0 & 3) * 8;
    const int r1 = g1 >> 2, c1 = (g1 & 3) * 8;

    for (int kt = 0; kt < ND; kt += 32) {
        gl_lds16(xb + (size_t)(m0 + r0) * ND + kt + c0, (char*)At + g0 * 16);
        gl_lds16(xb + (size_t)(m0 + r1) * ND + kt + c1, (char*)At + g1 * 16);
        gl_lds16(w + (size_t)(n0 + r0) * ND + kt + c0, (char*)Bt + g0 * 16);
        gl_lds16(w + (size_t)(n0 + r1) * ND + kt + c1, (char*)Bt + g1 * 16);
        __syncthreads();

        bf16x8 fa[4], fb[4];
#pragma unroll
        for (int i = 0; i < 4; i++)
            fa[i] = *(const bf16x8*)&At[(wm + i * 16 + fr) * 32 + ks * 8];
#pragma unroll
        for (int j = 0; j < 4; j++)
            fb[j] = *(const bf16x8*)&Bt[(wn + j * 16 + fr) * 32 + ks * 8];

        if (z < 2) {
#pragma unroll
            for (int i = 0; i < 4; i++)
#pragma unroll
                for (int j = 0; j < 4; j++)
                    acc[i][j] = mfma16(fa[i], fb[j], acc[i][j]);
        } else {
#pragma unroll
            for (int i = 0; i < 4; i++)
#pragma unroll
                for (int j = 0; j < 4; j++)
                    acc[i][j] = mfma16(fb[j], fa[i], acc[i][j]);
        }
        __syncthreads();
    }

    if (z < 2) {
        u16* dst = (z == 0) ? qh : kh;
#pragma unroll
        for (int i = 0; i < 4; i++)
#pragma unroll
            for (int j = 0; j < 4; j++)
#pragma unroll
                for (int r = 0; r < 4; r++) {
                    int mg = m0 + wm + i * 16 + ks * 4 + r;
                    int ng = n0 + wn + j * 16 + fr;
                    int b = mg >> 11, s = mg & 2047;
                    int hh = ng >> 6, dd = ng & 63;
                    dst[(((size_t)b * NH + hh) * NS + s) * HD + dd] =
                        f2bf(acc[i][j][r]);
                }
    } else {
#pragma unroll
        for (int i = 0; i < 4; i++)
#pragma unroll
            for (int j = 0; j < 4; j++)
#pragma unroll
                for (int r = 0; r < 4; r++) {
                    int ng = n0 + wn + j * 16 + ks * 4 + r;  // d-dim
                    int mg = m0 + wm + i * 16 + fr;          // s-dim
                    int b = mg >> 11, s = mg & 2047;
                    int hh = ng >> 6, dd = ng & 63;
                    vt[(((size_t)b * NH + hh) * HD + dd) * NS + s] =
                        f2bf(acc[i][j][r]);
                }
    }
}

// --- causal flash attention ------------------------------------------------
// 1-D grid of 512 blocks: bh = blk & 31 (XCD-affine), pair = blk >> 5.
// Block handles q-tiles {pair, 31-pair} (64 rows each, one 16-row fragment
// per wave per tile). KVBLK=64. Two chains per wave share K/V fragments.

template <bool MASKED>
__device__ __forceinline__ void sm_update(f32x4* sc, float* m, float* l,
                                          f32x4* o, u16* pl, int kv0, int q0,
                                          int fr, int ks) {
#pragma unroll
    for (int r = 0; r < 4; r++) {
        const int qg = q0 + ks * 4 + r;
        float s[4];
#pragma unroll
        for (int kf = 0; kf < 4; kf++) {
            s[kf] = sc[kf][r] * 0.125f;
            if (MASKED) {
                if (kv0 + kf * 16 + fr > qg) s[kf] = -1e30f;
            }
        }
        float pm = fmaxf(fmaxf(s[0], s[1]), fmaxf(s[2], s[3]));
        pm = fmaxf(pm, __shfl_xor(pm, 1));
        pm = fmaxf(pm, __shfl_xor(pm, 2));
        pm = fmaxf(pm, __shfl_xor(pm, 4));
        pm = fmaxf(pm, __shfl_xor(pm, 8));
        float mn = fmaxf(m[r], pm);
        float co = __expf(m[r] - mn);
        float p[4], rs = 0.f;
#pragma unroll
        for (int kf = 0; kf < 4; kf++) {
            p[kf] = __expf(s[kf] - mn);
            rs += p[kf];
        }
        rs += __shfl_xor(rs, 1);
        rs += __shfl_xor(rs, 2);
        rs += __shfl_xor(rs, 4);
        rs += __shfl_xor(rs, 8);
        l[r] = l[r] * co + rs;
        m[r] = mn;
#pragma unroll
        for (int j = 0; j < 4; j++) o[j][r] *= co;
        const int row = ks * 4 + r;
#pragma unroll
        for (int kf = 0; kf < 4; kf++) {
            int k = kf * 16 + fr;
            int c = (k >> 3) ^ (row & 7);  // XOR swizzle (16B chunks)
            *(u16*)((char*)pl + row * 128 + (c << 4) + ((k & 7) << 1)) =
                f2bf(p[kf]);
        }
    }
}

__device__ __forceinline__ void pv_step(const u16* __restrict__ V, u16* pl,
                                        f32x4* o, int kv0, int fr, int ks) {
    bf16x8 pa[2];
#pragma unroll
    for (int s = 0; s < 2; s++) {
        int c = (s * 4 + ks) ^ (fr & 7);
        pa[s] = *(const bf16x8*)((const char*)pl + fr * 128 + (c << 4));
    }
#pragma unroll
    for (int j = 0; j < 4; j++) {
#pragma unroll
        for (int s = 0; s < 2; s++) {
            bf16x8 fv = *(const bf16x8*)&V[(j * 16 + fr) * NS + kv0 + s * 32 +
                                           ks * 8];
            o[j] = mfma16(pa[s], fv, o[j]);
        }
    }
}

__device__ __forceinline__ void store_o(float* __restrict__ out, int b, int h,
                                        int q0, f32x4* o, float* l, int fr,
                                        int ks) {
    float rl[4];
#pragma unroll
    for (int r = 0; r < 4; r++) rl[r] = 1.0f / l[r];
#pragma unroll
    for (int j = 0; j < 4; j++)
#pragma unroll
        for (int r = 0; r < 4; r++) {
            int qg = q0 + ks * 4 + r;
            out[((size_t)b * NS + qg) * ND + h * HD + j * 16 + fr] =
                o[j][r] * rl[r];
        }
}

__global__ __launch_bounds__(256) void attn_k(const u16* __restrict__ qh,
                                              const u16* __restrict__ kh,
                                              const u16* __restrict__ vt,
                                              float* __restrict__ out) {
    const int t = threadIdx.x, lane = t & 63, wv = t >> 6;
    const int fr = lane & 15, ks = lane >> 4;
    const int bh = blockIdx.x & 31;  // low bits -> same XCD per head
    const int pair = blockIdx.x >> 5;
    const int b = bh >> 4, h = bh & 15;
    const int tileA = 31 - pair;  // heavy
    const int tileB = pair;       // light
    const int qA = tileA * 64 + wv * 16;
    const int qB = tileB * 64 + wv * 16;
    const u16* Q = qh + (size_t)bh * NS * HD;
    const u16* K = kh + (size_t)bh * NS * HD;
    const u16* V = vt + (size_t)bh * HD * NS;

    bf16x8 fqA[2], fqB[2];
#pragma unroll
    for (int sl = 0; sl < 2; sl++) {
        fqA[sl] = *(const bf16x8*)&Q[(qA + fr) * HD + sl * 32 + ks * 8];
        fqB[sl] = *(const bf16x8*)&Q[(qB + fr) * HD + sl * 32 + ks * 8];
    }

    float mA[4] = {-1e30f, -1e30f, -1e30f, -1e30f};
    float mB[4] = {-1e30f, -1e30f, -1e30f, -1e30f};
    float lA[4] = {}, lB[4] = {};
    f32x4 oA[4] = {}, oB[4] = {};

    __shared__ u16 P[4][2][16 * 64];
    u16* plA = &P[wv][0][0];
    u16* plB = &P[wv][1][0];

    const int nA = tileA + 1, nB = tileB + 1;  // 64-wide kv iterations
    for (int it = 0; it < nA; ++it) {
        const int kv0 = it * 64;
        bf16x8 fk[4][2];
#pragma unroll
        for (int kf = 0; kf < 4; kf++)
#pragma unroll
            for (int sl = 0; sl < 2; sl++)
                fk[kf][sl] = *(const bf16x8*)&K[(kv0 + kf * 16 + fr) * HD +
                                                sl * 32 + ks * 8];

        f32x4 scA[4] = {};
#pragma unroll
        for (int kf = 0; kf < 4; kf++) {
            scA[kf] = mfma16(fqA[0], fk[kf][0], scA[kf]);
            scA[kf] = mfma16(fqA[1], fk[kf][1], scA[kf]);
        }
        const bool doB = it < nB;
        f32x4 scB[4] = {};
        if (doB) {
#pragma unroll
            for (int kf = 0; kf < 4; kf++) {
                scB[kf] = mfma16(fqB[0], fk[kf][0], scB[kf]);
                scB[kf] = mfma16(fqB[1], fk[kf][1], scB[kf]);
            }
        }

        if (it == nA - 1)
            sm_update<true>(scA, mA, lA, oA, plA, kv0, qA, fr, ks);
        else
            sm_update<false>(scA, mA, lA, oA, plA, kv0, qA, fr, ks);
        if (doB) {
            if (it == nB - 1)
                sm_update<true>(scB, mB, lB, oB, plB, kv0, qB, fr, ks);
            else
                sm_update<false>(scB, mB, lB, oB, plB, kv0, qB, fr, ks);
        }

        pv_step(V, plA, oA, kv0, fr, ks);
        if (doB) pv_step(V, plB, oB, kv0, fr, ks);
    }

    store_o(out, b, h, qA, oA, lA, fr, ks);
    store_o(out, b, h, qB, oB, lB, fr, ks);
}

extern "C" void kernel_launch(void* const* d_in, const int* in_sizes, int n_in,
                              void* d_out, int out_size, void* d_ws,
                              size_t ws_size, hipStream_t stream) {
    const float* x = (const float*)d_in[0];
    const float* wq = (const float*)d_in[1];
    const float* wk = (const float*)d_in[2];
    const float* wvp = (const float*)d_in[3];
    float* out = (float*)d_out;

    char* w8 = (char*)d_ws;
    u16* xb = (u16*)(w8);                      // 8 MiB
    u16* wt = (u16*)(w8 + ((size_t)8 << 20));  // 6 MiB
    u16* qh = (u16*)(w8 + ((size_t)14 << 20));
    u16* kh = (u16*)(w8 + ((size_t)22 << 20));
    u16* vt = (u16*)(w8 + ((size_t)30 << 20));

    convx_k<<<(NB * NS * ND) / (256 * 8), 256, 0, stream>>>(x, xb);
    convw_k<<<dim3(ND / 32, ND / 32, 3), 256, 0, stream>>>(wq, wk, wvp, wt);
    qkv_gemm_k<<<dim3((NB * NS) / 128, ND / 128, 3), 256, 0, stream>>>(
        xb, wt, qh, kh, vt);
    attn_k<<<512, 256, 0, stream>>>(qh, kh, vt, out);
}